// Round 17
// baseline (66.277 us; speedup 1.0000x reference)
//
#include <hip/hip_runtime.h>
#include <hip/hip_bf16.h>

#define B_ 8
#define T_ 2048
#define C_ 1024
#define H_ 64

typedef __bf16 bf16x8 __attribute__((ext_vector_type(8)));
typedef float f32x4 __attribute__((ext_vector_type(4)));
typedef float f32x16 __attribute__((ext_vector_type(16)));

__device__ __forceinline__ unsigned short f2bf(float f) {
    union { float f; unsigned u; } v; v.f = f;
    unsigned u = v.u;
    u += 0x7fffu + ((u >> 16) & 1u);   // round-to-nearest-even
    return (unsigned short)(u >> 16);
}

#define GLOAD16(g, l) __builtin_amdgcn_global_load_lds( \
    (const __attribute__((address_space(1))) void*)(g), \
    (__attribute__((address_space(3))) void*)(l), 16, 0, 0)

#define MFMA16(a, b, c) __builtin_amdgcn_mfma_f32_16x16x32_bf16(a, b, c, 0, 0, 0)
#define MFMA32(a, b, c) __builtin_amdgcn_mfma_f32_32x32x16_bf16(a, b, c, 0, 0, 0)

// ---------- kernel 0: transpose+convert weights into wt[192][1024] bf16 ----------
__global__ __launch_bounds__(256) void wtrans_kernel(const float* __restrict__ wk,
                              const float* __restrict__ wq,
                              const float* __restrict__ wv,
                              unsigned short* __restrict__ wt) {
    __shared__ unsigned short ls[64][72];   // [c][k], padded
    const int m = blockIdx.x >> 4, kt = blockIdx.x & 15;
    const float* w = (m == 0) ? wk : (m == 1) ? wq : wv;
    const int tid = threadIdx.x;
    #pragma unroll
    for (int it = 0; it < 4; ++it) {
        int k = it * 16 + (tid >> 4);
        int c = (tid & 15) * 4;
        float4 f = *(const float4*)(w + (size_t)(kt * 64 + k) * 64 + c);
        ls[c][k] = f2bf(f.x); ls[c + 1][k] = f2bf(f.y);
        ls[c + 2][k] = f2bf(f.z); ls[c + 3][k] = f2bf(f.w);
    }
    __syncthreads();
    const int c = tid >> 2, kc = (tid & 3) * 16;
    unsigned short* dst = wt + (size_t)(m * 64 + c) * 1024 + kt * 64 + kc;
    *(uint4*)dst = *(const uint4*)&ls[c][kc];
    *(uint4*)(dst + 8) = *(const uint4*)&ls[c][kc + 8];
}

// ---------- kernel 1: fused QKV projection v6 ----------
// 32x32x16 MFMA: halves LDS fragment traffic per output row (the invariant
// cost across v2..v5). BM=64, 256 thr, 4 waves = 2 rt x 2 cg; wave = 32 rows
// x 96 cols (3 ct). LDS 2 x 40KB (x fp32 16KB + wt 24KB), 2 blocks/CU.
__global__ __launch_bounds__(256) void qkv_kernel(const float* __restrict__ x,
        const unsigned short* __restrict__ wt,
        unsigned short* __restrict__ kh,
        unsigned short* __restrict__ qh,
        unsigned short* __restrict__ vt) {
    __shared__ __attribute__((aligned(16))) char smem[2][40960];
    const int tid = threadIdx.x;
    const int wid = tid >> 6, lane = tid & 63;
    const int l31 = lane & 31, hi = lane >> 5;
    const int rt = wid & 1, cg = wid >> 1;
    const int row0 = blockIdx.x * 64;
    const char* xg = (const char*)x;
    const char* wtg = (const char*)wt;

    f32x16 acc[3] = {};

    auto stage = [&](char* buf, int k0) {
        #pragma unroll
        for (int R = 0; R < 4; ++R) {              // x: 64 rows x 256B = 16KB
            int o = R * 4096 + tid * 16;
            int row = o >> 8, inrow = o & 255;
            int src = inrow ^ ((row & 15) << 4);
            GLOAD16(xg + ((size_t)(row0 + row) * 4096 + (size_t)k0 * 4 + src), buf + o);
        }
        #pragma unroll
        for (int R = 0; R < 6; ++R) {              // wt: 192 rows x 128B = 24KB
            int o = R * 4096 + tid * 16;
            int row = o >> 7, inrow = o & 127;
            int src = inrow ^ ((row & 7) << 4);
            GLOAD16(wtg + ((size_t)row * 2048 + (size_t)k0 * 2 + src), buf + 16384 + o);
        }
    };

    stage(smem[0], 0);
    asm volatile("s_waitcnt vmcnt(0)" ::: "memory");
    __syncthreads();

    const int arow = rt * 32 + l31;
    const int aswz = (arow & 15) << 4;

    for (int t = 0; t < 16; ++t) {
        char* cur = smem[t & 1];
        if (t < 15) stage(smem[(t + 1) & 1], (t + 1) * 64);

        const char* xb = cur;
        const char* wb = cur + 16384;
        // A fragments: 32x32x16, lane holds A[row=l31][k=hi*8+i]; 4 frags cover k=64
        bf16x8 a4[4];
        #pragma unroll
        for (int f = 0; f < 4; ++f) {
            int off = f * 64 + hi * 32;
            float4 f0 = *(const float4*)(xb + arow * 256 + (off ^ aswz));
            float4 f1 = *(const float4*)(xb + arow * 256 + ((off + 16) ^ aswz));
            union { unsigned short u[8]; bf16x8 v; } u;
            u.u[0] = f2bf(f0.x); u.u[1] = f2bf(f0.y); u.u[2] = f2bf(f0.z); u.u[3] = f2bf(f0.w);
            u.u[4] = f2bf(f1.x); u.u[5] = f2bf(f1.y); u.u[6] = f2bf(f1.z); u.u[7] = f2bf(f1.w);
            a4[f] = u.v;
        }
        #pragma unroll
        for (int ct = 0; ct < 3; ++ct) {
            int brow = cg * 96 + ct * 32 + l31;
            int bswz = (brow & 7) << 4;
            #pragma unroll
            for (int f = 0; f < 4; ++f) {
                bf16x8 b = *(const bf16x8*)(wb + brow * 128 + ((f * 32 + hi * 16) ^ bswz));
                acc[ct] = MFMA32(a4[f], b, acc[ct]);
            }
        }
        asm volatile("s_waitcnt vmcnt(0)" ::: "memory");
        __syncthreads();
    }

    // epilogue: 32x32 C/D layout col=lane&31, row=(reg&3)+8*(reg>>2)+4*(lane>>5)
    #pragma unroll
    for (int ct = 0; ct < 3; ++ct) {
        int col = cg * 96 + ct * 32 + l31;
        int m = col >> 6, h = col & 63;
        #pragma unroll
        for (int reg = 0; reg < 16; ++reg) {
            int grow = row0 + rt * 32 + (reg & 3) + 8 * (reg >> 2) + 4 * hi;
            float val = acc[ct][reg];
            if (m == 0) {
                kh[(size_t)grow * H_ + h] = f2bf(val);
            } else if (m == 1) {
                qh[(size_t)grow * H_ + h] = f2bf(val * 0.03125f);  // C^-0.5
            } else {
                int bb = grow >> 11, tt = grow & (T_ - 1);
                vt[((size_t)bb * H_ + h) * T_ + tt] = f2bf(val);
            }
        }
    }
}

// ---------- kernel 2: causal flash attention (round-12 structure, unchanged) ----------
__global__ __launch_bounds__(256) void attn_kernel(const unsigned short* __restrict__ kh,
        const unsigned short* __restrict__ qh,
        const unsigned short* __restrict__ vt,
        float* __restrict__ out,
        float* __restrict__ po, float* __restrict__ pml, int split) {
    __shared__ __attribute__((aligned(16))) char kv[2][16384];   // K 8KB + V 8KB per buf
    __shared__ __attribute__((aligned(16))) char pl[4][2048];    // per-wave P tile [16 q][64 s] bf16
    const int tid = threadIdx.x;
    const int wid = tid >> 6, lane = tid & 63;
    const int lq = lane & 15, g = lane >> 4;

    int b, qt, c, nch;
    if (split) {
        int qtc = blockIdx.x >> 3; b = blockIdx.x & 7;
        qt = 31 - (qtc >> 3); c = qtc & 7;
        nch = (qt + 4) >> 2;          // ceil((qt*64+64)/256)
        if (c >= nch) return;
    } else {
        b = blockIdx.x & 7; qt = 31 - (blockIdx.x >> 3); c = 0; nch = 1;
    }
    const int qw = qt * 64 + wid * 16;
    const int q_glob = qw + lq;
    const int s_end_blk = qt * 64 + 64;
    const int sbeg = c << 8;
    const int send = (split && sbeg + 256 < s_end_blk) ? sbeg + 256 : s_end_blk;
    const int nt = (send - sbeg) >> 6;

    const char* khb = (const char*)kh + (size_t)b * T_ * H_ * 2;
    const char* vtb = (const char*)vt + (size_t)b * H_ * T_ * 2;
    const unsigned short* qhb = qh + (size_t)b * T_ * H_;

    bf16x8 qf0 = *(const bf16x8*)(qhb + (qw + lq) * H_ + g * 8);
    bf16x8 qf1 = *(const bf16x8*)(qhb + (qw + lq) * H_ + 32 + g * 8);

    auto stage = [&](char* buf, int s0) {
        #pragma unroll
        for (int R = 0; R < 2; ++R) {              // K tile: rows = s, 128B each
            int o = R * 4096 + wid * 1024;
            int ob = o + lane * 16;
            int row = ob >> 7, inrow = ob & 127;
            int src = inrow ^ ((row & 7) << 4);
            GLOAD16(khb + (size_t)(s0 + row) * 128 + src, buf + o);
        }
        #pragma unroll
        for (int R = 0; R < 2; ++R) {              // V tile: rows = h, 128B window of vt row
            int o = R * 4096 + wid * 1024;
            int ob = o + lane * 16;
            int row = ob >> 7, inrow = ob & 127;
            int src = inrow ^ ((row & 7) << 4);
            GLOAD16(vtb + (size_t)row * 4096 + (size_t)s0 * 2 + src, buf + 8192 + o);
        }
    };

    float m_run = -1e30f, l_run = 0.f;
    f32x4 o_acc[4] = {};
    char* pbase = pl[wid];
    const int pswz = (lq & 7) << 4;

    stage(kv[0], sbeg);
    asm volatile("s_waitcnt vmcnt(0)" ::: "memory");
    __syncthreads();

    for (int t = 0; t < nt; ++t) {
        const int s0 = sbeg + t * 64;
        char* cur = kv[t & 1];
        if (t + 1 < nt) stage(kv[(t + 1) & 1], s0 + 64);
        const bool domask = (s0 + 64 == s_end_blk);   // diagonal step

        // QK^T: sa[st] = K[s0+st*16..+16][:] . Q^T
        f32x4 sa[4];
        __builtin_amdgcn_s_setprio(1);
        #pragma unroll
        for (int st = 0; st < 4; ++st) {
            int row = st * 16 + lq;
            int swz = (row & 7) << 4;
            f32x4 a = {};
            bf16x8 k0 = *(const bf16x8*)(cur + row * 128 + ((g * 16) ^ swz));
            bf16x8 k1 = *(const bf16x8*)(cur + row * 128 + ((64 + g * 16) ^ swz));
            a = MFMA16(k0, qf0, a);
            a = MFMA16(k1, qf1, a);
            sa[st] = a;
        }
        __builtin_amdgcn_s_setprio(0);

        // online softmax (per-lane q = lq; s = s0 + st*16 + g*4 + r)
        float p[4][4];
        float smax = -1e30f;
        #pragma unroll
        for (int st = 0; st < 4; ++st)
            #pragma unroll
            for (int r = 0; r < 4; ++r) {
                float v = sa[st][r];
                if (domask) {
                    int sg = s0 + st * 16 + g * 4 + r;
                    v = (sg <= q_glob) ? v : -1e30f;
                }
                p[st][r] = v;
                smax = fmaxf(smax, v);
            }
        smax = fmaxf(smax, __shfl_xor(smax, 16));
        smax = fmaxf(smax, __shfl_xor(smax, 32));
        const float m_new = fmaxf(m_run, smax);
        const float alpha = __expf(m_run - m_new);
        float lsum = 0.f;
        #pragma unroll
        for (int st = 0; st < 4; ++st)
            #pragma unroll
            for (int r = 0; r < 4; ++r) {
                p[st][r] = __expf(p[st][r] - m_new);
                lsum += p[st][r];
            }
        lsum += __shfl_xor(lsum, 16);
        lsum += __shfl_xor(lsum, 32);
        l_run = l_run * alpha + lsum;
        m_run = m_new;
        #pragma unroll
        for (int hc = 0; hc < 4; ++hc) o_acc[hc] *= alpha;

        // write P (bf16) to per-wave LDS tile, swizzled rows
        #pragma unroll
        for (int st = 0; st < 4; ++st) {
            union { unsigned short u[4]; uint2 d; } pk;
            pk.u[0] = f2bf(p[st][0]); pk.u[1] = f2bf(p[st][1]);
            pk.u[2] = f2bf(p[st][2]); pk.u[3] = f2bf(p[st][3]);
            *(uint2*)(pbase + lq * 128 + ((st * 32 + g * 8) ^ pswz)) = pk.d;
        }

        // PV: o_acc[hc] += V^T[hc*16+lq][s0+ss*32..] . P^T
        __builtin_amdgcn_s_setprio(1);
        #pragma unroll
        for (int hc = 0; hc < 4; ++hc) {
            int row = hc * 16 + lq;
            int swz = (row & 7) << 4;
            #pragma unroll
            for (int ss = 0; ss < 2; ++ss) {
                bf16x8 vf = *(const bf16x8*)(cur + 8192 + row * 128 + ((ss * 64 + g * 16) ^ swz));
                bf16x8 pb = *(const bf16x8*)(pbase + lq * 128 + ((ss * 64 + g * 16) ^ pswz));
                o_acc[hc] = MFMA16(vf, pb, o_acc[hc]);
            }
        }
        __builtin_amdgcn_s_setprio(0);

        asm volatile("s_waitcnt vmcnt(0)" ::: "memory");
        __syncthreads();
    }

    if (nch == 1) {
        const float inv_l = 1.0f / l_run;
        float* ob = out + ((size_t)b * T_ + qw + lq) * H_;
        #pragma unroll
        for (int hc = 0; hc < 4; ++hc)
            #pragma unroll
            for (int r = 0; r < 4; ++r)
                ob[hc * 16 + g * 4 + r] = o_acc[hc][r] * inv_l;
    } else {
        const int slot = (b * 32 + qt) * 8 + c;
        float* poS = po + (size_t)slot * 4096;
        const int row = wid * 16 + lq;
        #pragma unroll
        for (int hc = 0; hc < 4; ++hc)
            #pragma unroll
            for (int r = 0; r < 4; ++r)
                poS[(size_t)row * 64 + hc * 16 + g * 4 + r] = o_acc[hc][r];
        if (g == 0) {
            pml[slot * 64 + row] = m_run;
            pml[131072 + slot * 64 + row] = l_run;
        }
    }
}

// ---------- kernel 3: combine v2 (round-12, unchanged) ----------
__global__ __launch_bounds__(256) void combine_kernel(const float* __restrict__ po,
        const float* __restrict__ pml, float* __restrict__ out) {
    const int bq = blockIdx.x >> 4, seg = blockIdx.x & 15;
    const int b = bq / 28, qt = 4 + bq % 28;
    const int nch = (qt + 4) >> 2;               // 2..9
    const int r = seg * 4 + (threadIdx.x >> 6);
    const int h = threadIdx.x & 63;
    const int base_slot = (b * 32 + qt) * 8;

    float mv[9], lv[9], ov[9];
    float m = -1e30f;
    #pragma unroll 9
    for (int cc = 0; cc < 9; ++cc) {
        if (cc < nch) {
            mv[cc] = pml[(base_slot + cc) * 64 + r];
            lv[cc] = pml[131072 + (base_slot + cc) * 64 + r];
            ov[cc] = po[(size_t)(base_slot + cc) * 4096 + r * 64 + h];
            m = fmaxf(m, mv[cc]);
        }
    }
    float lsum = 0.f, osum = 0.f;
    #pragma unroll 9
    for (int cc = 0; cc < 9; ++cc) {
        if (cc < nch) {
            float w = __expf(mv[cc] - m);
            lsum += lv[cc] * w;
            osum += ov[cc] * w;
        }
    }
    out[((size_t)b * T_ + qt * 64 + r) * H_ + h] = osum / lsum;
}

extern "C" void kernel_launch(void* const* d_in, const int* in_sizes, int n_in,
                              void* d_out, int out_size, void* d_ws, size_t ws_size,
                              hipStream_t stream) {
    const float* x  = (const float*)d_in[0];
    const float* wk = (const float*)d_in[1];
    const float* wq = (const float*)d_in[2];
    const float* wv = (const float*)d_in[3];
    float* out = (float*)d_out;

    char* ws = (char*)d_ws;
    unsigned short* kh = (unsigned short*)(ws);                            // 2 MB
    unsigned short* qh = (unsigned short*)(ws + (size_t)2 * 1024 * 1024);  // 2 MB
    unsigned short* vt = (unsigned short*)(ws + (size_t)4 * 1024 * 1024);  // 2 MB
    unsigned short* wt = (unsigned short*)(ws + (size_t)6 * 1024 * 1024);  // 384 KB
    float* po  = (float*)(ws + (size_t)8 * 1024 * 1024);                   // 32 MB
    float* pml = (float*)(ws + (size_t)40 * 1024 * 1024);                  // 1 MB

    const bool split = ws_size >= (size_t)42 * 1024 * 1024;

    wtrans_kernel<<<dim3(48), dim3(256), 0, stream>>>(wk, wq, wv, wt);
    qkv_kernel<<<dim3(256), dim3(256), 0, stream>>>(x, wt, kh, qh, vt);
    attn_kernel<<<dim3(split ? 2048 : 256), dim3(256), 0, stream>>>(kh, qh, vt, out, po, pml, split ? 1 : 0);
    if (split)
        combine_kernel<<<dim3(3584), dim3(256), 0, stream>>>(po, pml, out);
}

// Round 18
// 63.666 us; speedup vs baseline: 1.0410x; 1.0410x over previous
//
#include <hip/hip_runtime.h>
#include <hip/hip_bf16.h>

#define B_ 8
#define T_ 2048
#define C_ 1024
#define H_ 64

typedef __bf16 bf16x8 __attribute__((ext_vector_type(8)));
typedef float f32x4 __attribute__((ext_vector_type(4)));
typedef float f32x16 __attribute__((ext_vector_type(16)));

__device__ __forceinline__ unsigned short f2bf(float f) {
    union { float f; unsigned u; } v; v.f = f;
    unsigned u = v.u;
    u += 0x7fffu + ((u >> 16) & 1u);   // round-to-nearest-even
    return (unsigned short)(u >> 16);
}
// tasks per (b): qt 0..15, nch(qt) = (qt>>1)+1; cumq = sum_{j<qt} nch(j)
__device__ __forceinline__ int cumq(int j) {
    int h = j >> 1;
    return j + h * (h - 1) + (j & 1) * h;
}

#define GLOAD16(g, l) __builtin_amdgcn_global_load_lds( \
    (const __attribute__((address_space(1))) void*)(g), \
    (__attribute__((address_space(3))) void*)(l), 16, 0, 0)

#define MFMA16(a, b, c) __builtin_amdgcn_mfma_f32_16x16x32_bf16(a, b, c, 0, 0, 0)
#define MFMA32(a, b, c) __builtin_amdgcn_mfma_f32_32x32x16_bf16(a, b, c, 0, 0, 0)

// ---------- kernel 0: transpose+convert weights into wt[192][1024] bf16 ----------
__global__ __launch_bounds__(256) void wtrans_kernel(const float* __restrict__ wk,
                              const float* __restrict__ wq,
                              const float* __restrict__ wv,
                              unsigned short* __restrict__ wt) {
    __shared__ unsigned short ls[64][72];   // [c][k], padded
    const int m = blockIdx.x >> 4, kt = blockIdx.x & 15;
    const float* w = (m == 0) ? wk : (m == 1) ? wq : wv;
    const int tid = threadIdx.x;
    #pragma unroll
    for (int it = 0; it < 4; ++it) {
        int k = it * 16 + (tid >> 4);
        int c = (tid & 15) * 4;
        float4 f = *(const float4*)(w + (size_t)(kt * 64 + k) * 64 + c);
        ls[c][k] = f2bf(f.x); ls[c + 1][k] = f2bf(f.y);
        ls[c + 2][k] = f2bf(f.z); ls[c + 3][k] = f2bf(f.w);
    }
    __syncthreads();
    const int c = tid >> 2, kc = (tid & 3) * 16;
    unsigned short* dst = wt + (size_t)(m * 64 + c) * 1024 + kt * 64 + kc;
    *(uint4*)dst = *(const uint4*)&ls[c][kc];
    *(uint4*)(dst + 8) = *(const uint4*)&ls[c][kc + 8];
}

// ---------- kernel 1: fused QKV projection v5 (round-12, the 59.97 build) ----------
__global__ __launch_bounds__(256) void qkv_kernel(const float* __restrict__ x,
        const unsigned short* __restrict__ wt,
        unsigned short* __restrict__ kh,
        unsigned short* __restrict__ qh,
        unsigned short* __restrict__ vt) {
    __shared__ __attribute__((aligned(16))) char smem[2][32768];   // x 8KB + wt 24KB per buf
    const int tid = threadIdx.x;
    const int wid = tid >> 6, lane = tid & 63;
    const int lq = lane & 15, g = lane >> 4;
    const int rg = wid & 1, cg = wid >> 1;
    const int row0 = blockIdx.x * 32;
    const char* xg = (const char*)x;
    const char* wtg = (const char*)wt;

    f32x4 acc[6] = {};

    auto stage = [&](char* buf, int k0) {
        #pragma unroll
        for (int R = 0; R < 2; ++R) {              // x: 32 rows x 256B = 8KB
            int o = R * 4096 + tid * 16;
            int row = o >> 8, inrow = o & 255;
            int src = inrow ^ ((row & 15) << 4);
            GLOAD16(xg + ((size_t)(row0 + row) * 4096 + (size_t)k0 * 4 + src), buf + o);
        }
        #pragma unroll
        for (int R = 0; R < 6; ++R) {              // wt: 192 rows x 128B = 24KB
            int o = R * 4096 + tid * 16;
            int row = o >> 7, inrow = o & 127;
            int src = inrow ^ ((row & 7) << 4);
            GLOAD16(wtg + ((size_t)row * 2048 + (size_t)k0 * 2 + src), buf + 8192 + o);
        }
    };

    stage(smem[0], 0);
    asm volatile("s_waitcnt vmcnt(0)" ::: "memory");
    __syncthreads();

    for (int t = 0; t < 16; ++t) {
        char* cur = smem[t & 1];
        if (t < 15) stage(smem[(t + 1) & 1], (t + 1) * 64);

        const char* xb = cur;
        const char* wb = cur + 8192;
        bf16x8 a[2];
        #pragma unroll
        for (int ks = 0; ks < 2; ++ks) {
            int row = rg * 16 + lq;
            int kb0 = ks * 128 + g * 32;
            float4 f0 = *(const float4*)(xb + row * 256 + (kb0 ^ ((row & 15) << 4)));
            float4 f1 = *(const float4*)(xb + row * 256 + ((kb0 + 16) ^ ((row & 15) << 4)));
            union { unsigned short u[8]; bf16x8 v; } u;
            u.u[0] = f2bf(f0.x); u.u[1] = f2bf(f0.y); u.u[2] = f2bf(f0.z); u.u[3] = f2bf(f0.w);
            u.u[4] = f2bf(f1.x); u.u[5] = f2bf(f1.y); u.u[6] = f2bf(f1.z); u.u[7] = f2bf(f1.w);
            a[ks] = u.v;
        }
        #pragma unroll
        for (int j = 0; j < 6; ++j) {
            int row = cg * 96 + j * 16 + lq;
            #pragma unroll
            for (int ks = 0; ks < 2; ++ks) {
                int kb = ks * 64 + g * 16;
                bf16x8 bfrag = *(const bf16x8*)(wb + row * 128 + (kb ^ ((row & 7) << 4)));
                acc[j] = MFMA16(a[ks], bfrag, acc[j]);
            }
        }
        asm volatile("s_waitcnt vmcnt(0)" ::: "memory");
        __syncthreads();
    }

    #pragma unroll
    for (int j = 0; j < 6; ++j) {
        int col = cg * 96 + j * 16 + lq;
        int m = col >> 6, h = col & 63;
        #pragma unroll
        for (int r = 0; r < 4; ++r) {
            int grow = row0 + rg * 16 + g * 4 + r;
            float val = acc[j][r];
            if (m == 0) {
                kh[(size_t)grow * H_ + h] = f2bf(val);
            } else if (m == 1) {
                qh[(size_t)grow * H_ + h] = f2bf(val * 0.03125f);  // C^-0.5
            } else {
                int bb = grow >> 11, tt = grow & (T_ - 1);
                vt[((size_t)bb * H_ + h) * T_ + tt] = f2bf(val);
            }
        }
    }
}

// ---------- kernel 2: causal flash attention v7 — 32x32 MFMA, 32 q/wave ----------
// Block = 4 waves x 32 q = 128 q rows; KVBLK=64 double-buffered; 256-s chunks.
// Half the steps/barriers/softmax-chains of the 16x16 version; waves skip
// fully-masked steps (barriers kept).
__global__ __launch_bounds__(256) void attn_kernel(const unsigned short* __restrict__ kh,
        const unsigned short* __restrict__ qh,
        const unsigned short* __restrict__ vt,
        float* __restrict__ out,
        float* __restrict__ po, float* __restrict__ pml, int split) {
    __shared__ __attribute__((aligned(16))) char kv[2][16384];   // K 8KB + V 8KB per buf
    __shared__ __attribute__((aligned(16))) char pl[4][4096];    // per-wave P [32 q][64 s] bf16
    const int tid = threadIdx.x;
    const int wid = tid >> 6, lane = tid & 63;
    const int l31 = lane & 31, hi = lane >> 5;

    int b, qt, c, nch;
    if (split) {
        b = blockIdx.x & 7;
        int r = 71 - (blockIdx.x >> 3);          // heavy (large qt) first
        qt = 0;
        for (int j = 15; j >= 0; --j) { if (r >= cumq(j)) { qt = j; break; } }
        c = r - cumq(qt);
        nch = (qt >> 1) + 1;
    } else {
        b = blockIdx.x & 7; qt = 15 - (blockIdx.x >> 3); c = 0; nch = 1;
    }
    const int qw = qt * 128 + wid * 32;          // wave q base
    const int q_glob = qw + l31;
    const int s_end_blk = qt * 128 + 128;
    const int sbeg = c << 8;
    const int send = (split && sbeg + 256 < s_end_blk) ? sbeg + 256 : s_end_blk;
    const int nt = (send - sbeg) >> 6;

    const char* khb = (const char*)kh + ((size_t)b << 18);
    const char* vtb = (const char*)vt + ((size_t)b << 18);
    const unsigned short* qhb = qh + ((size_t)b << 17);

    // Q B-fragments: col=q=l31, k = f*16 + hi*8 + i
    bf16x8 qf[4];
    #pragma unroll
    for (int f = 0; f < 4; ++f)
        qf[f] = *(const bf16x8*)((const char*)(qhb + (size_t)(qw + l31) * H_) + f * 32 + hi * 16);

    auto stage = [&](char* buf, int s0) {
        #pragma unroll
        for (int R = 0; R < 2; ++R) {              // K tile: 64 s-rows x 128B
            int o = R * 4096 + wid * 1024;
            int ob = o + lane * 16;
            int row = ob >> 7, inrow = ob & 127;
            int src = inrow ^ ((row & 7) << 4);
            GLOAD16(khb + (size_t)(s0 + row) * 128 + src, buf + o);
        }
        #pragma unroll
        for (int R = 0; R < 2; ++R) {              // V tile: 64 h-rows x 128B window
            int o = R * 4096 + wid * 1024;
            int ob = o + lane * 16;
            int row = ob >> 7, inrow = ob & 127;
            int src = inrow ^ ((row & 7) << 4);
            GLOAD16(vtb + (size_t)row * 4096 + (size_t)s0 * 2 + src, buf + 8192 + o);
        }
    };

    float m_run = -1e30f, l_run = 0.f;
    f32x16 o0 = {}, o1 = {};
    char* pbase = pl[wid];
    const int pswz = (l31 & 7) << 4;
    const int kswz = (l31 & 7) << 4;             // (32+l31)&7 == l31&7

    stage(kv[0], sbeg);
    asm volatile("s_waitcnt vmcnt(0)" ::: "memory");
    __syncthreads();

    for (int t = 0; t < nt; ++t) {
        const int s0 = sbeg + t * 64;
        char* cur = kv[t & 1];
        if (t + 1 < nt) stage(kv[(t + 1) & 1], s0 + 64);
        const bool active = (s0 < qw + 32);       // wave-uniform

        if (active) {
            const bool domask = (s0 + 64 > qw);
            // QK^T: S^T tiles [32 s][32 q], A=K rows, B=Q
            f32x16 sa0 = {}, sa1 = {};
            __builtin_amdgcn_s_setprio(1);
            #pragma unroll
            for (int f = 0; f < 4; ++f) {
                bf16x8 k0 = *(const bf16x8*)(cur + l31 * 128 + ((f * 32 + hi * 16) ^ kswz));
                bf16x8 k1 = *(const bf16x8*)(cur + (32 + l31) * 128 + ((f * 32 + hi * 16) ^ kswz));
                sa0 = MFMA32(k0, qf[f], sa0);
                sa1 = MFMA32(k1, qf[f], sa1);
            }
            __builtin_amdgcn_s_setprio(0);

            // mask + max (per-lane q = l31; s-row = (r&3)+8*(r>>2)+4*hi + st*32)
            float p0[16], p1[16];
            float smax = -1e30f;
            #pragma unroll
            for (int r = 0; r < 16; ++r) {
                int srow = (r & 3) + 8 * (r >> 2) + 4 * hi;
                float v0 = sa0[r], v1 = sa1[r];
                if (domask) {
                    if (s0 + srow > q_glob) v0 = -1e30f;
                    if (s0 + 32 + srow > q_glob) v1 = -1e30f;
                }
                p0[r] = v0; p1[r] = v1;
                smax = fmaxf(smax, fmaxf(v0, v1));
            }
            smax = fmaxf(smax, __shfl_xor(smax, 32));
            const float m_new = fmaxf(m_run, smax);
            const float alpha = __expf(m_run - m_new);
            float lsum = 0.f;
            #pragma unroll
            for (int r = 0; r < 16; ++r) {
                p0[r] = __expf(p0[r] - m_new);
                p1[r] = __expf(p1[r] - m_new);
                lsum += p0[r] + p1[r];
            }
            lsum += __shfl_xor(lsum, 32);
            l_run = l_run * alpha + lsum;
            m_run = m_new;
            o0 *= alpha; o1 *= alpha;

            // pack P^T [q=l31][s] bf16: s = st*32 + rq*8 + hi*4 + (0..3)
            #pragma unroll
            for (int rq = 0; rq < 4; ++rq) {
                uint2 d0, d1;
                d0.x = (unsigned)f2bf(p0[rq * 4 + 0]) | ((unsigned)f2bf(p0[rq * 4 + 1]) << 16);
                d0.y = (unsigned)f2bf(p0[rq * 4 + 2]) | ((unsigned)f2bf(p0[rq * 4 + 3]) << 16);
                d1.x = (unsigned)f2bf(p1[rq * 4 + 0]) | ((unsigned)f2bf(p1[rq * 4 + 1]) << 16);
                d1.y = (unsigned)f2bf(p1[rq * 4 + 2]) | ((unsigned)f2bf(p1[rq * 4 + 3]) << 16);
                *(uint2*)(pbase + l31 * 128 + ((rq * 16 + hi * 8) ^ pswz)) = d0;
                *(uint2*)(pbase + l31 * 128 + ((64 + rq * 16 + hi * 8) ^ pswz)) = d1;
            }

            // PV: O^T[h][q] += V^T . P^T ; A=V rows (h), B=P (col=q, k=s)
            __builtin_amdgcn_s_setprio(1);
            #pragma unroll
            for (int f = 0; f < 4; ++f) {
                bf16x8 pb = *(const bf16x8*)(pbase + l31 * 128 + ((f * 32 + hi * 16) ^ pswz));
                bf16x8 v0 = *(const bf16x8*)(cur + 8192 + l31 * 128 + ((f * 32 + hi * 16) ^ kswz));
                bf16x8 v1 = *(const bf16x8*)(cur + 8192 + (32 + l31) * 128 + ((f * 32 + hi * 16) ^ kswz));
                o0 = MFMA32(v0, pb, o0);
                o1 = MFMA32(v1, pb, o1);
            }
            __builtin_amdgcn_s_setprio(0);
        }

        asm volatile("s_waitcnt vmcnt(0)" ::: "memory");
        __syncthreads();
    }

    // D layout: col=q=l31, row=h=(reg&3)+8*(reg>>2)+4*hi (+32 for o1)
    if (nch == 1) {
        const float inv_l = 1.0f / l_run;
        float* ob = out + ((size_t)b * T_ + qw + l31) * H_;
        #pragma unroll
        for (int rq = 0; rq < 4; ++rq) {
            float4 s0v, s1v;
            s0v.x = o0[rq * 4 + 0] * inv_l; s0v.y = o0[rq * 4 + 1] * inv_l;
            s0v.z = o0[rq * 4 + 2] * inv_l; s0v.w = o0[rq * 4 + 3] * inv_l;
            s1v.x = o1[rq * 4 + 0] * inv_l; s1v.y = o1[rq * 4 + 1] * inv_l;
            s1v.z = o1[rq * 4 + 2] * inv_l; s1v.w = o1[rq * 4 + 3] * inv_l;
            *(float4*)(ob + rq * 8 + hi * 4) = s0v;
            *(float4*)(ob + 32 + rq * 8 + hi * 4) = s1v;
        }
    } else {
        const int slot = b * 72 + cumq(qt) + c;
        float* poS = po + (size_t)slot * 8192 + (size_t)(wid * 32 + l31) * 64;
        #pragma unroll
        for (int rq = 0; rq < 4; ++rq) {
            float4 s0v, s1v;
            s0v.x = o0[rq * 4 + 0]; s0v.y = o0[rq * 4 + 1];
            s0v.z = o0[rq * 4 + 2]; s0v.w = o0[rq * 4 + 3];
            s1v.x = o1[rq * 4 + 0]; s1v.y = o1[rq * 4 + 1];
            s1v.z = o1[rq * 4 + 2]; s1v.w = o1[rq * 4 + 3];
            *(float4*)(poS + rq * 8 + hi * 4) = s0v;
            *(float4*)(poS + 32 + rq * 8 + hi * 4) = s1v;
        }
        if (hi == 0) {
            pml[slot * 128 + wid * 32 + l31] = m_run;
            pml[73728 + slot * 128 + wid * 32 + l31] = l_run;
        }
    }
}

// ---------- kernel 3: combine — 128-q slots, <=8 chunks, all loads parallel ----------
// grid: 8 b x 14 qt(2..15) x 32 seg = 3584 blocks
__global__ __launch_bounds__(256) void combine_kernel(const float* __restrict__ po,
        const float* __restrict__ pml, float* __restrict__ out) {
    const int b = blockIdx.x / 448;
    const int rem = blockIdx.x % 448;
    const int qt = 2 + rem / 32, seg = rem % 32;
    const int nch = (qt >> 1) + 1;               // 2..8
    const int r = seg * 4 + (threadIdx.x >> 6);  // 0..127
    const int h = threadIdx.x & 63;
    const int base_slot = b * 72 + cumq(qt);

    float mv[8], lv[8], ov[8];
    float m = -1e30f;
    #pragma unroll 8
    for (int cc = 0; cc < 8; ++cc) {
        if (cc < nch) {
            mv[cc] = pml[(base_slot + cc) * 128 + r];
            lv[cc] = pml[73728 + (base_slot + cc) * 128 + r];
            ov[cc] = po[(size_t)(base_slot + cc) * 8192 + r * 64 + h];
            m = fmaxf(m, mv[cc]);
        }
    }
    float lsum = 0.f, osum = 0.f;
    #pragma unroll 8
    for (int cc = 0; cc < 8; ++cc) {
        if (cc < nch) {
            float w = __expf(mv[cc] - m);
            lsum += lv[cc] * w;
            osum += ov[cc] * w;
        }
    }
    out[((size_t)b * T_ + qt * 128 + r) * H_ + h] = osum / lsum;
}

extern "C" void kernel_launch(void* const* d_in, const int* in_sizes, int n_in,
                              void* d_out, int out_size, void* d_ws, size_t ws_size,
                              hipStream_t stream) {
    const float* x  = (const float*)d_in[0];
    const float* wk = (const float*)d_in[1];
    const float* wq = (const float*)d_in[2];
    const float* wv = (const float*)d_in[3];
    float* out = (float*)d_out;

    char* ws = (char*)d_ws;
    unsigned short* kh = (unsigned short*)(ws);                            // 2 MB
    unsigned short* qh = (unsigned short*)(ws + (size_t)2 * 1024 * 1024);  // 2 MB
    unsigned short* vt = (unsigned short*)(ws + (size_t)4 * 1024 * 1024);  // 2 MB
    unsigned short* wt = (unsigned short*)(ws + (size_t)6 * 1024 * 1024);  // 384 KB
    float* po  = (float*)(ws + (size_t)8 * 1024 * 1024);                   // 18.9 MB (576 slots x 128 x 64)
    float* pml = (float*)(ws + (size_t)28 * 1024 * 1024);                  // 590 KB

    const bool split = ws_size >= (size_t)30 * 1024 * 1024;

    wtrans_kernel<<<dim3(48), dim3(256), 0, stream>>>(wk, wq, wv, wt);
    qkv_kernel<<<dim3(512), dim3(256), 0, stream>>>(x, wt, kh, qh, vt);
    attn_kernel<<<dim3(split ? 576 : 128), dim3(256), 0, stream>>>(kh, qh, vt, out, po, pml, split ? 1 : 0);
    if (split)
        combine_kernel<<<dim3(3584), dim3(256), 0, stream>>>(po, pml, out);
}